// Round 1
// baseline (1097.364 us; speedup 1.0000x reference)
//
#include <hip/hip_runtime.h>
#include <hip/hip_bf16.h>
#include <math.h>

#define TOK   4096
#define EDIM  512
#define HEADS 8
#define DHEAD 64

// ---------------------------------------------------------------------------
// Wave (64-lane) reductions
// ---------------------------------------------------------------------------
__device__ __forceinline__ float waveMax(float v) {
#pragma unroll
    for (int off = 32; off > 0; off >>= 1)
        v = fmaxf(v, __shfl_xor(v, off, 64));
    return v;
}
__device__ __forceinline__ float waveSum(float v) {
#pragma unroll
    for (int off = 32; off > 0; off >>= 1)
        v += __shfl_xor(v, off, 64);
    return v;
}

// ---------------------------------------------------------------------------
// linear: Y[M,Nout] = X[M,K] @ W[Nout,K]^T + b     (torch Linear)
// 64x64 tile, BK=16, 256 threads (16x16), 4x4 acc per thread, f32.
// ---------------------------------------------------------------------------
__global__ __launch_bounds__(256) void linear_kernel(
    const float* __restrict__ X, const float* __restrict__ W,
    const float* __restrict__ b, float* __restrict__ Y,
    int M, int Nout, int K)
{
    __shared__ float Xs[64][17];
    __shared__ float Ws[64][17];

    const int tx = threadIdx.x, ty = threadIdx.y;
    const int t  = ty * 16 + tx;
    const int row0 = blockIdx.y * 64;
    const int col0 = blockIdx.x * 64;

    const int lr = t >> 2;          // 0..63
    const int lc = (t & 3) * 4;     // 0,4,8,12

    float acc[4][4] = {};

    for (int k0 = 0; k0 < K; k0 += 16) {
        float4 xv = *(const float4*)(X + (size_t)(row0 + lr) * K + k0 + lc);
        float4 wv = *(const float4*)(W + (size_t)(col0 + lr) * K + k0 + lc);
        Xs[lr][lc + 0] = xv.x; Xs[lr][lc + 1] = xv.y;
        Xs[lr][lc + 2] = xv.z; Xs[lr][lc + 3] = xv.w;
        Ws[lr][lc + 0] = wv.x; Ws[lr][lc + 1] = wv.y;
        Ws[lr][lc + 2] = wv.z; Ws[lr][lc + 3] = wv.w;
        __syncthreads();
#pragma unroll
        for (int k = 0; k < 16; ++k) {
            float a[4], bb[4];
#pragma unroll
            for (int i = 0; i < 4; ++i) a[i]  = Xs[ty * 4 + i][k];
#pragma unroll
            for (int j = 0; j < 4; ++j) bb[j] = Ws[tx * 4 + j][k];
#pragma unroll
            for (int i = 0; i < 4; ++i)
#pragma unroll
                for (int j = 0; j < 4; ++j)
                    acc[i][j] = fmaf(a[i], bb[j], acc[i][j]);
        }
        __syncthreads();
    }

#pragma unroll
    for (int i = 0; i < 4; ++i) {
        const int row = row0 + ty * 4 + i;
        float4 o;
        o.x = acc[i][0] + b[col0 + tx * 4 + 0];
        o.y = acc[i][1] + b[col0 + tx * 4 + 1];
        o.z = acc[i][2] + b[col0 + tx * 4 + 2];
        o.w = acc[i][3] + b[col0 + tx * 4 + 3];
        *(float4*)(Y + (size_t)row * Nout + col0 + tx * 4) = o;
    }
}

// ---------------------------------------------------------------------------
// scores: attn_logits[h,n,m] = (1/8) * sum_d Q[n, h*64+d] * K[m, h*64+d]
// 64x64 output tile per block, full K=64 staged in LDS.
// grid: (TOK/64 m-blocks, TOK/64 n-blocks, HEADS)
// ---------------------------------------------------------------------------
__global__ __launch_bounds__(256) void scores_kernel(
    const float* __restrict__ Q, const float* __restrict__ Kmat,
    float* __restrict__ attn)
{
    __shared__ float Qs[64][65];
    __shared__ float Ks[64][65];

    const int tx = threadIdx.x, ty = threadIdx.y;
    const int t  = ty * 16 + tx;
    const int m0 = blockIdx.x * 64;
    const int n0 = blockIdx.y * 64;
    const int h  = blockIdx.z;

    const int lr  = t >> 2;          // 0..63
    const int lc0 = (t & 3) * 16;    // 0,16,32,48

    const float* Qp = Q    + (size_t)(n0 + lr) * EDIM + h * DHEAD + lc0;
    const float* Kp = Kmat + (size_t)(m0 + lr) * EDIM + h * DHEAD + lc0;
#pragma unroll
    for (int u = 0; u < 4; ++u) {
        float4 qv = *(const float4*)(Qp + 4 * u);
        float4 kv = *(const float4*)(Kp + 4 * u);
        Qs[lr][lc0 + 4 * u + 0] = qv.x; Qs[lr][lc0 + 4 * u + 1] = qv.y;
        Qs[lr][lc0 + 4 * u + 2] = qv.z; Qs[lr][lc0 + 4 * u + 3] = qv.w;
        Ks[lr][lc0 + 4 * u + 0] = kv.x; Ks[lr][lc0 + 4 * u + 1] = kv.y;
        Ks[lr][lc0 + 4 * u + 2] = kv.z; Ks[lr][lc0 + 4 * u + 3] = kv.w;
    }
    __syncthreads();

    float acc[4][4] = {};
#pragma unroll 8
    for (int k = 0; k < 64; ++k) {
        float a[4], bb[4];
#pragma unroll
        for (int i = 0; i < 4; ++i) a[i]  = Qs[ty * 4 + i][k];
#pragma unroll
        for (int j = 0; j < 4; ++j) bb[j] = Ks[tx * 4 + j][k];
#pragma unroll
        for (int i = 0; i < 4; ++i)
#pragma unroll
            for (int j = 0; j < 4; ++j)
                acc[i][j] = fmaf(a[i], bb[j], acc[i][j]);
    }

    float* dst = attn + (size_t)h * TOK * TOK + (size_t)n0 * TOK + m0;
#pragma unroll
    for (int i = 0; i < 4; ++i) {
        float4 o;
        o.x = acc[i][0] * 0.125f; o.y = acc[i][1] * 0.125f;
        o.z = acc[i][2] * 0.125f; o.w = acc[i][3] * 0.125f;
        *(float4*)(dst + (size_t)(ty * 4 + i) * TOK + tx * 4) = o;
    }
}

// ---------------------------------------------------------------------------
// softmax in-place over each attn row (length TOK). One 256-thread block/row.
// grid: (TOK, HEADS)
// ---------------------------------------------------------------------------
__global__ __launch_bounds__(256) void softmax_kernel(float* __restrict__ attn)
{
    const int n = blockIdx.x, h = blockIdx.y;
    float* row = attn + ((size_t)h * TOK + n) * TOK;
    const int t = threadIdx.x;
    const int lane = t & 63, wid = t >> 6;

    __shared__ float red[8];

    float v[16];
    float mx = -INFINITY;
#pragma unroll
    for (int i = 0; i < 16; ++i) {
        v[i] = row[t + i * 256];
        mx = fmaxf(mx, v[i]);
    }
    mx = waveMax(mx);
    if (lane == 0) red[wid] = mx;
    __syncthreads();
    mx = fmaxf(fmaxf(red[0], red[1]), fmaxf(red[2], red[3]));

    float s = 0.f;
#pragma unroll
    for (int i = 0; i < 16; ++i) {
        v[i] = __expf(v[i] - mx);
        s += v[i];
    }
    s = waveSum(s);
    if (lane == 0) red[4 + wid] = s;
    __syncthreads();
    s = (red[4] + red[5]) + (red[6] + red[7]);

    const float inv = 1.0f / s;
#pragma unroll
    for (int i = 0; i < 16; ++i)
        row[t + i * 256] = v[i] * inv;
}

// ---------------------------------------------------------------------------
// ctx[n, h*64+d] = sum_m attn[h,n,m] * V[m, h*64+d]
// per block: 64 rows x full 64 d, BK=16 over m. grid: (TOK/64, HEADS)
// ---------------------------------------------------------------------------
__global__ __launch_bounds__(256) void ctx_kernel(
    const float* __restrict__ attn, const float* __restrict__ V,
    float* __restrict__ ctx)
{
    __shared__ float Ps[64][17];
    __shared__ float Vs[16][68];

    const int tx = threadIdx.x, ty = threadIdx.y;
    const int t  = ty * 16 + tx;
    const int n0 = blockIdx.x * 64;
    const int h  = blockIdx.y;

    const float* Pbase = attn + (size_t)h * TOK * TOK;

    const int pr = t >> 2,  pc = (t & 3) * 4;    // P: row pr, cols pc..pc+3
    const int vr = t >> 4,  vc = (t & 15) * 4;   // V: row vr, cols vc..vc+3

    float acc[4][4] = {};

    for (int m0 = 0; m0 < TOK; m0 += 16) {
        float4 pv = *(const float4*)(Pbase + (size_t)(n0 + pr) * TOK + m0 + pc);
        float4 vv = *(const float4*)(V + (size_t)(m0 + vr) * EDIM + h * DHEAD + vc);
        Ps[pr][pc + 0] = pv.x; Ps[pr][pc + 1] = pv.y;
        Ps[pr][pc + 2] = pv.z; Ps[pr][pc + 3] = pv.w;
        Vs[vr][vc + 0] = vv.x; Vs[vr][vc + 1] = vv.y;
        Vs[vr][vc + 2] = vv.z; Vs[vr][vc + 3] = vv.w;
        __syncthreads();
#pragma unroll
        for (int k = 0; k < 16; ++k) {
            float a[4], bb[4];
#pragma unroll
            for (int i = 0; i < 4; ++i) a[i]  = Ps[ty * 4 + i][k];
#pragma unroll
            for (int j = 0; j < 4; ++j) bb[j] = Vs[k][tx * 4 + j];
#pragma unroll
            for (int i = 0; i < 4; ++i)
#pragma unroll
                for (int j = 0; j < 4; ++j)
                    acc[i][j] = fmaf(a[i], bb[j], acc[i][j]);
        }
        __syncthreads();
    }

#pragma unroll
    for (int i = 0; i < 4; ++i) {
        const int row = n0 + ty * 4 + i;
        float4 o;
        o.x = acc[i][0]; o.y = acc[i][1]; o.z = acc[i][2]; o.w = acc[i][3];
        *(float4*)(ctx + (size_t)row * EDIM + h * DHEAD + tx * 4) = o;
    }
}

// ---------------------------------------------------------------------------
// launch
// ---------------------------------------------------------------------------
extern "C" void kernel_launch(void* const* d_in, const int* in_sizes, int n_in,
                              void* d_out, int out_size, void* d_ws, size_t ws_size,
                              hipStream_t stream) {
    (void)in_sizes; (void)n_in; (void)out_size; (void)ws_size;

    const float* x  = (const float*)d_in[0];
    const float* Wq = (const float*)d_in[1];
    const float* bq = (const float*)d_in[2];
    const float* Wk = (const float*)d_in[3];
    const float* bk = (const float*)d_in[4];
    const float* Wv = (const float*)d_in[5];
    const float* bv = (const float*)d_in[6];
    const float* Wo = (const float*)d_in[7];
    const float* bo = (const float*)d_in[8];

    float* out  = (float*)d_out;                       // [TOK, EDIM]
    float* attn = out  + (size_t)TOK * EDIM;           // [HEADS, TOK, TOK]
    float* Qb   = attn + (size_t)HEADS * TOK * TOK;    // [TOK, EDIM]
    float* Kb   = Qb   + (size_t)TOK * EDIM;
    float* Vb   = Kb   + (size_t)TOK * EDIM;
    float* ctx  = (float*)d_ws;                        // [TOK, EDIM] scratch (8 MB)

    dim3 blk(16, 16);
    dim3 gl(EDIM / 64, TOK / 64);

    linear_kernel<<<gl, blk, 0, stream>>>(x, Wq, bq, Qb, TOK, EDIM, EDIM);
    linear_kernel<<<gl, blk, 0, stream>>>(x, Wk, bk, Kb, TOK, EDIM, EDIM);
    linear_kernel<<<gl, blk, 0, stream>>>(x, Wv, bv, Vb, TOK, EDIM, EDIM);

    dim3 gs(TOK / 64, TOK / 64, HEADS);
    scores_kernel<<<gs, blk, 0, stream>>>(Qb, Kb, attn);

    softmax_kernel<<<dim3(TOK, HEADS), 256, 0, stream>>>(attn);

    ctx_kernel<<<dim3(TOK / 64, HEADS), blk, 0, stream>>>(attn, Vb, ctx);

    linear_kernel<<<gl, blk, 0, stream>>>(ctx, Wo, bo, out, TOK, EDIM, EDIM);
}

// Round 2
// 617.366 us; speedup vs baseline: 1.7775x; 1.7775x over previous
//
#include <hip/hip_runtime.h>
#include <hip/hip_bf16.h>
#include <math.h>

#define TOK   4096
#define EDIM  512
#define HEADS 8
#define DHEAD 64

typedef __attribute__((ext_vector_type(8))) short short8v;
typedef __attribute__((ext_vector_type(4))) float float4v;

__device__ __forceinline__ unsigned short f2bf(float f) {
    unsigned int u = __float_as_uint(f);
    unsigned int r = (u + 0x7FFFu + ((u >> 16) & 1u)) >> 16;
    return (unsigned short)r;
}

// ---------------------------------------------------------------------------
// linear: Y[M,Nout] = X[M,K] @ W[Nout,K]^T + b   (f32, exact — verified R1)
// ---------------------------------------------------------------------------
__global__ __launch_bounds__(256) void linear_kernel(
    const float* __restrict__ X, const float* __restrict__ W,
    const float* __restrict__ b, float* __restrict__ Y,
    int M, int Nout, int K)
{
    __shared__ float Xs[64][17];
    __shared__ float Ws[64][17];

    const int tx = threadIdx.x, ty = threadIdx.y;
    const int t  = ty * 16 + tx;
    const int row0 = blockIdx.y * 64;
    const int col0 = blockIdx.x * 64;

    const int lr = t >> 2;
    const int lc = (t & 3) * 4;

    float acc[4][4] = {};

    for (int k0 = 0; k0 < K; k0 += 16) {
        float4 xv = *(const float4*)(X + (size_t)(row0 + lr) * K + k0 + lc);
        float4 wv = *(const float4*)(W + (size_t)(col0 + lr) * K + k0 + lc);
        Xs[lr][lc + 0] = xv.x; Xs[lr][lc + 1] = xv.y;
        Xs[lr][lc + 2] = xv.z; Xs[lr][lc + 3] = xv.w;
        Ws[lr][lc + 0] = wv.x; Ws[lr][lc + 1] = wv.y;
        Ws[lr][lc + 2] = wv.z; Ws[lr][lc + 3] = wv.w;
        __syncthreads();
#pragma unroll
        for (int k = 0; k < 16; ++k) {
            float a[4], bb[4];
#pragma unroll
            for (int i = 0; i < 4; ++i) a[i]  = Xs[ty * 4 + i][k];
#pragma unroll
            for (int j = 0; j < 4; ++j) bb[j] = Ws[tx * 4 + j][k];
#pragma unroll
            for (int i = 0; i < 4; ++i)
#pragma unroll
                for (int j = 0; j < 4; ++j)
                    acc[i][j] = fmaf(a[i], bb[j], acc[i][j]);
        }
        __syncthreads();
    }

#pragma unroll
    for (int i = 0; i < 4; ++i) {
        const int row = row0 + ty * 4 + i;
        float4 o;
        o.x = acc[i][0] + b[col0 + tx * 4 + 0];
        o.y = acc[i][1] + b[col0 + tx * 4 + 1];
        o.z = acc[i][2] + b[col0 + tx * 4 + 2];
        o.w = acc[i][3] + b[col0 + tx * 4 + 3];
        *(float4*)(Y + (size_t)row * Nout + col0 + tx * 4) = o;
    }
}

// ---------------------------------------------------------------------------
// prep: Kb[h][m][d] (bf16) from K[m][h*64+d] (f32). Fully coalesced.
// ---------------------------------------------------------------------------
__global__ __launch_bounds__(256) void prep_kb_kernel(
    const float* __restrict__ K, unsigned short* __restrict__ Kb)
{
    const int gid  = blockIdx.x * 256 + threadIdx.x;
    const int base = gid * 8;
    const int m  = base >> 9;
    const int e0 = base & 511;
    const int h  = e0 >> 6;
    const int d  = e0 & 63;
    float4 a = *(const float4*)(K + (size_t)m * EDIM + e0);
    float4 b = *(const float4*)(K + (size_t)m * EDIM + e0 + 4);
    short8v o;
    o[0] = (short)f2bf(a.x); o[1] = (short)f2bf(a.y);
    o[2] = (short)f2bf(a.z); o[3] = (short)f2bf(a.w);
    o[4] = (short)f2bf(b.x); o[5] = (short)f2bf(b.y);
    o[6] = (short)f2bf(b.z); o[7] = (short)f2bf(b.w);
    *(short8v*)(Kb + ((size_t)h * TOK + m) * DHEAD + d) = o;
}

// ---------------------------------------------------------------------------
// prep: Vt[h][d][m] (bf16) from V[m][h*64+d] (f32), via LDS tile transpose.
// grid: (TOK/64, HEADS), 256 threads.
// ---------------------------------------------------------------------------
__global__ __launch_bounds__(256) void prep_vt_kernel(
    const float* __restrict__ V, unsigned short* __restrict__ Vt)
{
    __shared__ unsigned short Vs[64][80];   // row stride 160 B (16B-aligned)
    const int t  = threadIdx.x;
    const int m0 = blockIdx.x * 64;
    const int h  = blockIdx.y;
    {
        const int mm = t >> 2;
        const int dg = (t & 3) * 16;
        const float* p = V + (size_t)(m0 + mm) * EDIM + h * DHEAD + dg;
#pragma unroll
        for (int q = 0; q < 4; ++q) {
            float4 v = *(const float4*)(p + q * 4);
            Vs[dg + q * 4 + 0][mm] = f2bf(v.x);
            Vs[dg + q * 4 + 1][mm] = f2bf(v.y);
            Vs[dg + q * 4 + 2][mm] = f2bf(v.z);
            Vs[dg + q * 4 + 3][mm] = f2bf(v.w);
        }
    }
    __syncthreads();
    {
        const int dd = t >> 2;
        const int mg = (t & 3) * 16;
        unsigned short* dst = Vt + ((size_t)h * DHEAD + dd) * TOK + m0 + mg;
        *(short8v*)(dst)     = *(const short8v*)&Vs[dd][mg];
        *(short8v*)(dst + 8) = *(const short8v*)&Vs[dd][mg + 8];
    }
}

// ---------------------------------------------------------------------------
// fused attention: per block = (16 query rows) x (1 head).
// 8 waves; wave w owns key columns [w*512, w*512+512).
// S held in registers (32 mfma C-frags/wave), block-wide softmax stats,
// attn written once (normalized f32), PV via wave-private LDS P-transpose.
// ---------------------------------------------------------------------------
__global__ __launch_bounds__(512, 2) void fused_attn_kernel(
    const float* __restrict__ Q,            // [TOK][EDIM] f32
    const unsigned short* __restrict__ Kb,  // [H][TOK][64] bf16
    const unsigned short* __restrict__ Vt,  // [H][64][TOK] bf16
    float* __restrict__ attn,               // [H][TOK][TOK] f32
    float* __restrict__ ctx)                // [TOK][EDIM] f32
{
    __shared__ alignas(16) char lds_raw[33 * 1024];
    float* redM = (float*)(lds_raw + 32 * 1024);   // [16][8]
    float* redS = redM + 16 * 8;                   // [16][8]

    const int t    = threadIdx.x;
    const int lane = t & 63;
    const int w    = t >> 6;          // wave 0..7
    const int l15  = lane & 15;
    const int g4   = lane >> 4;       // 0..3
    const int h    = blockIdx.y;
    const int n0   = blockIdx.x * 16;
    const int mw   = w * 512;

    // ---- Q A-fragments (16 rows x K=64), f32 -> bf16 ----
    short8v aq[2];
    {
        const float* qp = Q + (size_t)(n0 + l15) * EDIM + h * DHEAD + g4 * 8;
#pragma unroll
        for (int ks = 0; ks < 2; ++ks) {
            float4 u = *(const float4*)(qp + ks * 32);
            float4 v = *(const float4*)(qp + ks * 32 + 4);
            aq[ks][0] = (short)f2bf(u.x); aq[ks][1] = (short)f2bf(u.y);
            aq[ks][2] = (short)f2bf(u.z); aq[ks][3] = (short)f2bf(u.w);
            aq[ks][4] = (short)f2bf(v.x); aq[ks][5] = (short)f2bf(v.y);
            aq[ks][6] = (short)f2bf(v.z); aq[ks][7] = (short)f2bf(v.w);
        }
    }

    // ---- QK^T: S[16 x 512] per wave, 32 C-frags ----
    float4v s[8][4];
#pragma unroll
    for (int c = 0; c < 8; ++c)
#pragma unroll
        for (int mt = 0; mt < 4; ++mt)
            s[c][mt] = (float4v){0.f, 0.f, 0.f, 0.f};

    const unsigned short* KbH = Kb + (size_t)h * TOK * DHEAD;
#pragma unroll
    for (int c = 0; c < 8; ++c) {
        const int mbase = mw + c * 64;
#pragma unroll
        for (int mt = 0; mt < 4; ++mt) {
            const unsigned short* kp =
                KbH + (size_t)(mbase + mt * 16 + l15) * DHEAD + g4 * 8;
            short8v b0 = *(const short8v*)(kp);
            short8v b1 = *(const short8v*)(kp + 32);
            s[c][mt] = __builtin_amdgcn_mfma_f32_16x16x32_bf16(aq[0], b0, s[c][mt], 0, 0, 0);
            s[c][mt] = __builtin_amdgcn_mfma_f32_16x16x32_bf16(aq[1], b1, s[c][mt], 0, 0, 0);
        }
    }

    // ---- row max (raw logits), block-wide ----
    float mx4[4] = {-INFINITY, -INFINITY, -INFINITY, -INFINITY};
#pragma unroll
    for (int c = 0; c < 8; ++c)
#pragma unroll
        for (int mt = 0; mt < 4; ++mt)
#pragma unroll
            for (int r = 0; r < 4; ++r)
                mx4[r] = fmaxf(mx4[r], s[c][mt][r]);
#pragma unroll
    for (int off = 1; off <= 8; off <<= 1)
#pragma unroll
        for (int r = 0; r < 4; ++r)
            mx4[r] = fmaxf(mx4[r], __shfl_xor(mx4[r], off, 64));
    if (l15 == 0) {
#pragma unroll
        for (int r = 0; r < 4; ++r)
            redM[(g4 * 4 + r) * 8 + w] = mx4[r];
    }
    __syncthreads();
    float mx[4];
#pragma unroll
    for (int r = 0; r < 4; ++r) {
        const float* rp = redM + (g4 * 4 + r) * 8;
        float4 A = *(const float4*)rp;
        float4 B = *(const float4*)(rp + 4);
        mx[r] = fmaxf(fmaxf(fmaxf(A.x, A.y), fmaxf(A.z, A.w)),
                      fmaxf(fmaxf(B.x, B.y), fmaxf(B.z, B.w))) * 0.125f;
    }

    // ---- exp (scaled) + row sum, block-wide ----
    float sm4[4] = {0.f, 0.f, 0.f, 0.f};
#pragma unroll
    for (int c = 0; c < 8; ++c)
#pragma unroll
        for (int mt = 0; mt < 4; ++mt)
#pragma unroll
            for (int r = 0; r < 4; ++r) {
                float p = __expf(s[c][mt][r] * 0.125f - mx[r]);
                s[c][mt][r] = p;
                sm4[r] += p;
            }
#pragma unroll
    for (int off = 1; off <= 8; off <<= 1)
#pragma unroll
        for (int r = 0; r < 4; ++r)
            sm4[r] += __shfl_xor(sm4[r], off, 64);
    if (l15 == 0) {
#pragma unroll
        for (int r = 0; r < 4; ++r)
            redS[(g4 * 4 + r) * 8 + w] = sm4[r];
    }
    __syncthreads();
    float inv[4];
#pragma unroll
    for (int r = 0; r < 4; ++r) {
        const float* rp = redS + (g4 * 4 + r) * 8;
        float4 A = *(const float4*)rp;
        float4 B = *(const float4*)(rp + 4);
        inv[r] = 1.0f / ((A.x + A.y) + (A.z + A.w) + ((B.x + B.y) + (B.z + B.w)));
    }

    // ---- normalize + write attn + PV ----
    float* attnH = attn + ((size_t)h * TOK + n0) * TOK;
    char*  pl    = lds_raw + w * 2048;   // wave-private P tile [16][64] bf16, XOR-swizzled
    const unsigned short* VtH = Vt + (size_t)h * DHEAD * TOK;
    float4v cacc[4];
#pragma unroll
    for (int dt = 0; dt < 4; ++dt) cacc[dt] = (float4v){0.f, 0.f, 0.f, 0.f};

#pragma unroll
    for (int c = 0; c < 8; ++c) {
        const int mbase = mw + c * 64;
#pragma unroll
        for (int mt = 0; mt < 4; ++mt) {
            const int mcol = mt * 16 + l15;
#pragma unroll
            for (int r = 0; r < 4; ++r) {
                const int row = g4 * 4 + r;
                float pv = s[c][mt][r] * inv[r];
                attnH[(size_t)row * TOK + mbase + mcol] = pv;
                const int byt = (row * 128 + mcol * 2) ^ ((row & 7) << 4);
                *(unsigned short*)(pl + byt) = f2bf(pv);
            }
        }
        asm volatile("s_waitcnt lgkmcnt(0)" ::: "memory");
        __builtin_amdgcn_sched_barrier(0);
        short8v pa[2];
#pragma unroll
        for (int ks = 0; ks < 2; ++ks) {
            const int byt = (l15 * 128 + ks * 64 + g4 * 16) ^ ((l15 & 7) << 4);
            pa[ks] = *(const short8v*)(pl + byt);
        }
#pragma unroll
        for (int dt = 0; dt < 4; ++dt) {
            const unsigned short* vp =
                VtH + (size_t)(dt * 16 + l15) * TOK + mbase + g4 * 8;
            short8v v0 = *(const short8v*)(vp);
            short8v v1 = *(const short8v*)(vp + 32);
            cacc[dt] = __builtin_amdgcn_mfma_f32_16x16x32_bf16(pa[0], v0, cacc[dt], 0, 0, 0);
            cacc[dt] = __builtin_amdgcn_mfma_f32_16x16x32_bf16(pa[1], v1, cacc[dt], 0, 0, 0);
        }
    }

    // ---- cross-wave ctx reduction (reuses P region after barrier) ----
    __syncthreads();
    float* ctxred = (float*)lds_raw;   // [8][16][64] f32 = 32 KB
#pragma unroll
    for (int dt = 0; dt < 4; ++dt)
#pragma unroll
        for (int r = 0; r < 4; ++r)
            ctxred[(w * 16 + g4 * 4 + r) * 64 + dt * 16 + l15] = cacc[dt][r];
    __syncthreads();
    for (int e = t; e < 1024; e += 512) {
        const int n = e >> 6, d = e & 63;
        float acc = 0.f;
#pragma unroll
        for (int w2 = 0; w2 < 8; ++w2)
            acc += ctxred[(w2 * 16 + n) * 64 + d];
        ctx[(size_t)(n0 + n) * EDIM + h * DHEAD + d] = acc;
    }
}

// ---------------------------------------------------------------------------
// launch
// ---------------------------------------------------------------------------
extern "C" void kernel_launch(void* const* d_in, const int* in_sizes, int n_in,
                              void* d_out, int out_size, void* d_ws, size_t ws_size,
                              hipStream_t stream) {
    (void)in_sizes; (void)n_in; (void)out_size; (void)ws_size;

    const float* x  = (const float*)d_in[0];
    const float* Wq = (const float*)d_in[1];
    const float* bq = (const float*)d_in[2];
    const float* Wk = (const float*)d_in[3];
    const float* bk = (const float*)d_in[4];
    const float* Wv = (const float*)d_in[5];
    const float* bv = (const float*)d_in[6];
    const float* Wo = (const float*)d_in[7];
    const float* bo = (const float*)d_in[8];

    float* out  = (float*)d_out;                       // [TOK, EDIM]
    float* attn = out  + (size_t)TOK * EDIM;           // [H, TOK, TOK]
    float* Qb   = attn + (size_t)HEADS * TOK * TOK;    // [TOK, EDIM]
    float* Kf   = Qb   + (size_t)TOK * EDIM;
    float* Vf   = Kf   + (size_t)TOK * EDIM;

    unsigned short* KbW = (unsigned short*)d_ws;                 // 4 MB
    unsigned short* VtW = KbW + (size_t)HEADS * TOK * DHEAD;     // 4 MB
    float* ctxW = (float*)((char*)d_ws + 8u * 1024u * 1024u);    // 8 MB

    dim3 blk(16, 16);
    dim3 gl(EDIM / 64, TOK / 64);

    linear_kernel<<<gl, blk, 0, stream>>>(x, Wq, bq, Qb, TOK, EDIM, EDIM);
    linear_kernel<<<gl, blk, 0, stream>>>(x, Wk, bk, Kf, TOK, EDIM, EDIM);
    linear_kernel<<<gl, blk, 0, stream>>>(x, Wv, bv, Vf, TOK, EDIM, EDIM);

    prep_kb_kernel<<<(TOK * EDIM / 8) / 256, 256, 0, stream>>>(Kf, KbW);
    prep_vt_kernel<<<dim3(TOK / 64, HEADS), 256, 0, stream>>>(Vf, VtW);

    fused_attn_kernel<<<dim3(TOK / 16, HEADS), 512, 0, stream>>>(Qb, KbW, VtW, attn, ctxW);

    linear_kernel<<<gl, blk, 0, stream>>>(ctxW, Wo, bo, out, TOK, EDIM, EDIM);
}

// Round 3
// 603.967 us; speedup vs baseline: 1.8169x; 1.0222x over previous
//
#include <hip/hip_runtime.h>
#include <hip/hip_bf16.h>
#include <math.h>

#define TOK   4096
#define EDIM  512
#define HEADS 8
#define DHEAD 64

typedef __attribute__((ext_vector_type(8))) short short8v;
typedef __attribute__((ext_vector_type(4))) float float4v;
typedef __attribute__((ext_vector_type(4))) unsigned int uint4v;

__device__ __forceinline__ unsigned short f2bf(float f) {
    unsigned int u = __float_as_uint(f);
    unsigned int r = (u + 0x7FFFu + ((u >> 16) & 1u)) >> 16;
    return (unsigned short)r;
}
__device__ __forceinline__ unsigned int packbf2(float a, float b) {
    return (unsigned int)f2bf(a) | ((unsigned int)f2bf(b) << 16);
}

// ---------------------------------------------------------------------------
// linear: Y[M,Nout] = X[M,K] @ W[Nout,K]^T + b   (f32, exact — verified R1)
// ---------------------------------------------------------------------------
__global__ __launch_bounds__(256) void linear_kernel(
    const float* __restrict__ X, const float* __restrict__ W,
    const float* __restrict__ b, float* __restrict__ Y,
    int M, int Nout, int K)
{
    __shared__ float Xs[64][17];
    __shared__ float Ws[64][17];

    const int tx = threadIdx.x, ty = threadIdx.y;
    const int t  = ty * 16 + tx;
    const int row0 = blockIdx.y * 64;
    const int col0 = blockIdx.x * 64;

    const int lr = t >> 2;
    const int lc = (t & 3) * 4;

    float acc[4][4] = {};

    for (int k0 = 0; k0 < K; k0 += 16) {
        float4 xv = *(const float4*)(X + (size_t)(row0 + lr) * K + k0 + lc);
        float4 wv = *(const float4*)(W + (size_t)(col0 + lr) * K + k0 + lc);
        Xs[lr][lc + 0] = xv.x; Xs[lr][lc + 1] = xv.y;
        Xs[lr][lc + 2] = xv.z; Xs[lr][lc + 3] = xv.w;
        Ws[lr][lc + 0] = wv.x; Ws[lr][lc + 1] = wv.y;
        Ws[lr][lc + 2] = wv.z; Ws[lr][lc + 3] = wv.w;
        __syncthreads();
#pragma unroll
        for (int k = 0; k < 16; ++k) {
            float a[4], bb[4];
#pragma unroll
            for (int i = 0; i < 4; ++i) a[i]  = Xs[ty * 4 + i][k];
#pragma unroll
            for (int j = 0; j < 4; ++j) bb[j] = Ws[tx * 4 + j][k];
#pragma unroll
            for (int i = 0; i < 4; ++i)
#pragma unroll
                for (int j = 0; j < 4; ++j)
                    acc[i][j] = fmaf(a[i], bb[j], acc[i][j]);
        }
        __syncthreads();
    }

#pragma unroll
    for (int i = 0; i < 4; ++i) {
        const int row = row0 + ty * 4 + i;
        float4 o;
        o.x = acc[i][0] + b[col0 + tx * 4 + 0];
        o.y = acc[i][1] + b[col0 + tx * 4 + 1];
        o.z = acc[i][2] + b[col0 + tx * 4 + 2];
        o.w = acc[i][3] + b[col0 + tx * 4 + 3];
        *(float4*)(Y + (size_t)row * Nout + col0 + tx * 4) = o;
    }
}

// ---------------------------------------------------------------------------
// prep: Kb[h][m][d] (bf16) from K[m][h*64+d] (f32).
// ---------------------------------------------------------------------------
__global__ __launch_bounds__(256) void prep_kb_kernel(
    const float* __restrict__ K, unsigned short* __restrict__ Kb)
{
    const int gid  = blockIdx.x * 256 + threadIdx.x;
    const int base = gid * 8;
    const int m  = base >> 9;
    const int e0 = base & 511;
    const int h  = e0 >> 6;
    const int d  = e0 & 63;
    float4 a = *(const float4*)(K + (size_t)m * EDIM + e0);
    float4 b = *(const float4*)(K + (size_t)m * EDIM + e0 + 4);
    short8v o;
    o[0] = (short)f2bf(a.x); o[1] = (short)f2bf(a.y);
    o[2] = (short)f2bf(a.z); o[3] = (short)f2bf(a.w);
    o[4] = (short)f2bf(b.x); o[5] = (short)f2bf(b.y);
    o[6] = (short)f2bf(b.z); o[7] = (short)f2bf(b.w);
    *(short8v*)(Kb + ((size_t)h * TOK + m) * DHEAD + d) = o;
}

// ---------------------------------------------------------------------------
// prep: Vt[h][d][m] (bf16) from V[m][h*64+d] (f32), LDS tile transpose.
// ---------------------------------------------------------------------------
__global__ __launch_bounds__(256) void prep_vt_kernel(
    const float* __restrict__ V, unsigned short* __restrict__ Vt)
{
    __shared__ unsigned short Vs[64][80];
    const int t  = threadIdx.x;
    const int m0 = blockIdx.x * 64;
    const int h  = blockIdx.y;
    {
        const int mm = t >> 2;
        const int dg = (t & 3) * 16;
        const float* p = V + (size_t)(m0 + mm) * EDIM + h * DHEAD + dg;
#pragma unroll
        for (int q = 0; q < 4; ++q) {
            float4 v = *(const float4*)(p + q * 4);
            Vs[dg + q * 4 + 0][mm] = f2bf(v.x);
            Vs[dg + q * 4 + 1][mm] = f2bf(v.y);
            Vs[dg + q * 4 + 2][mm] = f2bf(v.z);
            Vs[dg + q * 4 + 3][mm] = f2bf(v.w);
        }
    }
    __syncthreads();
    {
        const int dd = t >> 2;
        const int mg = (t & 3) * 16;
        unsigned short* dst = Vt + ((size_t)h * DHEAD + dd) * TOK + m0 + mg;
        *(short8v*)(dst)     = *(const short8v*)&Vs[dd][mg];
        *(short8v*)(dst + 8) = *(const short8v*)&Vs[dd][mg + 8];
    }
}

// ---------------------------------------------------------------------------
// fused attention, two-pass, S^T register layout.
// Block = 16 query rows x 1 head, 4 waves; wave w owns m in [w*1024, w*1024+1024).
// Pass 1: QK^T -> online (max,sum) per row.  Pass 2: recompute QK^T,
// normalize, float4 nontemporal attn store, shuffle-transpose P, PV MFMA.
// Lane layout (per 16x16 frag, swapped operands A=K,B=Q):
//   n (query row) = lane&15, m = frag_m0 + (lane>>4)*4 + r.
// ---------------------------------------------------------------------------
__global__ __launch_bounds__(256, 3) void fused_attn_kernel(
    const float* __restrict__ Q,            // [TOK][EDIM] f32
    const unsigned short* __restrict__ Kb,  // [H][TOK][64] bf16
    const unsigned short* __restrict__ Vt,  // [H][64][TOK] bf16
    float* __restrict__ attn,               // [H][TOK][TOK] f32
    float* __restrict__ ctx)                // [TOK][EDIM] f32
{
    __shared__ float ctxred[4 * 16 * 64];   // 16 KB
    __shared__ float redM[16 * 4];
    __shared__ float redS[16 * 4];

    const int t    = threadIdx.x;
    const int lane = t & 63;
    const int w    = t >> 6;          // wave 0..3
    const int l15  = lane & 15;       // query row within tile
    const int g4   = lane >> 4;       // 0..3
    const int h    = blockIdx.y;
    const int n0   = blockIdx.x * 16;

    const unsigned short* KbH = Kb + (size_t)h * TOK * DHEAD;
    const unsigned short* VtH = Vt + (size_t)h * DHEAD * TOK;

    // ---- Q B-fragment (col = n = l15, k = d = g4*8+j) ----
    short8v bq[2];
    {
        const float* qp = Q + (size_t)(n0 + l15) * EDIM + h * DHEAD + g4 * 8;
#pragma unroll
        for (int ks = 0; ks < 2; ++ks) {
            float4 u = *(const float4*)(qp + ks * 32);
            float4 v = *(const float4*)(qp + ks * 32 + 4);
            bq[ks][0] = (short)f2bf(u.x); bq[ks][1] = (short)f2bf(u.y);
            bq[ks][2] = (short)f2bf(u.z); bq[ks][3] = (short)f2bf(u.w);
            bq[ks][4] = (short)f2bf(v.x); bq[ks][5] = (short)f2bf(v.y);
            bq[ks][6] = (short)f2bf(v.z); bq[ks][7] = (short)f2bf(v.w);
        }
    }

    // ================= pass 1: stats =================
    float mrun = -INFINITY, srun = 0.f;
#pragma unroll 4
    for (int c = 0; c < 16; ++c) {
        const int mbase = w * 1024 + c * 64;
        float4v s[4];
#pragma unroll
        for (int mt = 0; mt < 4; ++mt) {
            const unsigned short* kp =
                KbH + (size_t)(mbase + mt * 16 + l15) * DHEAD + g4 * 8;
            short8v k0 = *(const short8v*)(kp);
            short8v k1 = *(const short8v*)(kp + 32);
            float4v sv = (float4v){0.f, 0.f, 0.f, 0.f};
            sv = __builtin_amdgcn_mfma_f32_16x16x32_bf16(k0, bq[0], sv, 0, 0, 0);
            sv = __builtin_amdgcn_mfma_f32_16x16x32_bf16(k1, bq[1], sv, 0, 0, 0);
            s[mt] = sv * 0.125f;
        }
        float cm = -INFINITY;
#pragma unroll
        for (int mt = 0; mt < 4; ++mt)
#pragma unroll
            for (int r = 0; r < 4; ++r)
                cm = fmaxf(cm, s[mt][r]);
        const float nm = fmaxf(mrun, cm);
        srun *= __expf(mrun - nm);
#pragma unroll
        for (int mt = 0; mt < 4; ++mt)
#pragma unroll
            for (int r = 0; r < 4; ++r)
                srun += __expf(s[mt][r] - nm);
        mrun = nm;
    }
    // cross-lane (g4) merge: lanes {l15, +16, +32, +48} share row n
#pragma unroll
    for (int off = 16; off <= 32; off <<= 1) {
        const float om = __shfl_xor(mrun, off, 64);
        const float os = __shfl_xor(srun, off, 64);
        const float nm = fmaxf(mrun, om);
        srun = srun * __expf(mrun - nm) + os * __expf(om - nm);
        mrun = nm;
    }
    if (lane < 16) {
        redM[l15 * 4 + w] = mrun;
        redS[l15 * 4 + w] = srun;
    }
    __syncthreads();
    float mx, inv;
    {
        float M = -INFINITY;
#pragma unroll
        for (int w2 = 0; w2 < 4; ++w2) M = fmaxf(M, redM[l15 * 4 + w2]);
        float S = 0.f;
#pragma unroll
        for (int w2 = 0; w2 < 4; ++w2)
            S += redS[l15 * 4 + w2] * __expf(redM[l15 * 4 + w2] - M);
        mx  = M;
        inv = 1.0f / S;
    }

    // ================= pass 2: recompute, store attn, PV =================
    float* attnH = attn + ((size_t)h * TOK + n0) * TOK;
    float4v cacc[4];
#pragma unroll
    for (int dt = 0; dt < 4; ++dt) cacc[dt] = (float4v){0.f, 0.f, 0.f, 0.f};

#pragma unroll 2
    for (int c = 0; c < 16; ++c) {
        const int mbase = w * 1024 + c * 64;
        unsigned int u[4][2];
#pragma unroll
        for (int mt = 0; mt < 4; ++mt) {
            const unsigned short* kp =
                KbH + (size_t)(mbase + mt * 16 + l15) * DHEAD + g4 * 8;
            short8v k0 = *(const short8v*)(kp);
            short8v k1 = *(const short8v*)(kp + 32);
            float4v sv = (float4v){0.f, 0.f, 0.f, 0.f};
            sv = __builtin_amdgcn_mfma_f32_16x16x32_bf16(k0, bq[0], sv, 0, 0, 0);
            sv = __builtin_amdgcn_mfma_f32_16x16x32_bf16(k1, bq[1], sv, 0, 0, 0);
            float4v p;
#pragma unroll
            for (int r = 0; r < 4; ++r)
                p[r] = __expf(sv[r] * 0.125f - mx) * inv;
            __builtin_nontemporal_store(
                p, (float4v*)(attnH + (size_t)l15 * TOK + mbase + mt * 16 + g4 * 4));
            u[mt][0] = packbf2(p[0], p[1]);
            u[mt][1] = packbf2(p[2], p[3]);
        }
        // shuffle-transpose: build A-frags P[n=l15][k = ks*32 + g4*8 + j]
        short8v pa[2];
#pragma unroll
        for (int ks = 0; ks < 2; ++ks) {
            const int sA = l15 + ((lane & 16) << 1);   // l15 + 32*(g4&1)
            const int sB = sA + 16;
            // both candidate fragments from both source lanes, select at dest
            unsigned int lo0 = __shfl(u[2 * ks][0], sA, 64);
            unsigned int lo1 = __shfl(u[2 * ks][1], sA, 64);
            unsigned int lo2 = __shfl(u[2 * ks][0], sB, 64);
            unsigned int lo3 = __shfl(u[2 * ks][1], sB, 64);
            unsigned int hi0 = __shfl(u[2 * ks + 1][0], sA, 64);
            unsigned int hi1 = __shfl(u[2 * ks + 1][1], sA, 64);
            unsigned int hi2 = __shfl(u[2 * ks + 1][0], sB, 64);
            unsigned int hi3 = __shfl(u[2 * ks + 1][1], sB, 64);
            uint4v wv;
            wv[0] = (g4 & 2) ? hi0 : lo0;
            wv[1] = (g4 & 2) ? hi1 : lo1;
            wv[2] = (g4 & 2) ? hi2 : lo2;
            wv[3] = (g4 & 2) ? hi3 : lo3;
            pa[ks] = __builtin_bit_cast(short8v, wv);
        }
#pragma unroll
        for (int dt = 0; dt < 4; ++dt) {
            const unsigned short* vp =
                VtH + (size_t)(dt * 16 + l15) * TOK + mbase + g4 * 8;
            short8v v0 = *(const short8v*)(vp);
            short8v v1 = *(const short8v*)(vp + 32);
            cacc[dt] = __builtin_amdgcn_mfma_f32_16x16x32_bf16(pa[0], v0, cacc[dt], 0, 0, 0);
            cacc[dt] = __builtin_amdgcn_mfma_f32_16x16x32_bf16(pa[1], v1, cacc[dt], 0, 0, 0);
        }
    }

    // ---- cross-wave ctx reduction ----
    __syncthreads();
#pragma unroll
    for (int dt = 0; dt < 4; ++dt)
#pragma unroll
        for (int r = 0; r < 4; ++r)
            ctxred[(w * 16 + g4 * 4 + r) * 64 + dt * 16 + l15] = cacc[dt][r];
    __syncthreads();
#pragma unroll
    for (int e = t; e < 1024; e += 256) {
        const int n = e >> 6, d = e & 63;
        float acc = 0.f;
#pragma unroll
        for (int w2 = 0; w2 < 4; ++w2)
            acc += ctxred[(w2 * 16 + n) * 64 + d];
        ctx[(size_t)(n0 + n) * EDIM + h * DHEAD + d] = acc;
    }
}

// ---------------------------------------------------------------------------
// launch
// ---------------------------------------------------------------------------
extern "C" void kernel_launch(void* const* d_in, const int* in_sizes, int n_in,
                              void* d_out, int out_size, void* d_ws, size_t ws_size,
                              hipStream_t stream) {
    (void)in_sizes; (void)n_in; (void)out_size; (void)ws_size;

    const float* x  = (const float*)d_in[0];
    const float* Wq = (const float*)d_in[1];
    const float* bq = (const float*)d_in[2];
    const float* Wk = (const float*)d_in[3];
    const float* bk = (const float*)d_in[4];
    const float* Wv = (const float*)d_in[5];
    const float* bv = (const float*)d_in[6];
    const float* Wo = (const float*)d_in[7];
    const float* bo = (const float*)d_in[8];

    float* out  = (float*)d_out;                       // [TOK, EDIM]
    float* attn = out  + (size_t)TOK * EDIM;           // [H, TOK, TOK]
    float* Qb   = attn + (size_t)HEADS * TOK * TOK;    // [TOK, EDIM]
    float* Kf   = Qb   + (size_t)TOK * EDIM;
    float* Vf   = Kf   + (size_t)TOK * EDIM;

    unsigned short* KbW = (unsigned short*)d_ws;                 // 4 MB
    unsigned short* VtW = KbW + (size_t)HEADS * TOK * DHEAD;     // 4 MB
    float* ctxW = (float*)((char*)d_ws + 8u * 1024u * 1024u);    // 8 MB

    dim3 blk(16, 16);
    dim3 gl(EDIM / 64, TOK / 64);

    linear_kernel<<<gl, blk, 0, stream>>>(x, Wq, bq, Qb, TOK, EDIM, EDIM);
    linear_kernel<<<gl, blk, 0, stream>>>(x, Wk, bk, Kf, TOK, EDIM, EDIM);
    linear_kernel<<<gl, blk, 0, stream>>>(x, Wv, bv, Vf, TOK, EDIM, EDIM);

    prep_kb_kernel<<<(TOK * EDIM / 8) / 256, 256, 0, stream>>>(Kf, KbW);
    prep_vt_kernel<<<dim3(TOK / 64, HEADS), 256, 0, stream>>>(Vf, VtW);

    fused_attn_kernel<<<dim3(TOK / 16, HEADS), 256, 0, stream>>>(Qb, KbW, VtW, attn, ctxW);

    linear_kernel<<<gl, blk, 0, stream>>>(ctxW, Wo, bo, out, TOK, EDIM, EDIM);
}

// Round 4
// 246.715 us; speedup vs baseline: 4.4479x; 2.4480x over previous
//
#include <hip/hip_runtime.h>
#include <hip/hip_bf16.h>
#include <math.h>

#define TOK   4096
#define EDIM  512
#define HEADS 8
#define DHEAD 64

typedef __attribute__((ext_vector_type(8))) short short8v;
typedef __attribute__((ext_vector_type(4))) float float4v;
typedef __attribute__((ext_vector_type(4))) unsigned int uint4v;

#define SC2 0.180336880111f   /* 0.125 * log2(e) */

__device__ __forceinline__ unsigned short f2bf(float f) {
    unsigned int u = __float_as_uint(f);
    unsigned int r = (u + 0x7FFFu + ((u >> 16) & 1u)) >> 16;
    return (unsigned short)r;
}
// pack (truncating round) bf16(lo) | bf16(hi)<<16 in one v_perm_b32
__device__ __forceinline__ unsigned int packbf_tr(float lo, float hi) {
    return __builtin_amdgcn_perm(__float_as_uint(hi), __float_as_uint(lo), 0x07060302u);
}
__device__ __forceinline__ float fast_exp2(float x) {
#if __has_builtin(__builtin_amdgcn_exp2f)
    return __builtin_amdgcn_exp2f(x);
#else
    return __expf(x * 0.69314718f);
#endif
}

// ---------------------------------------------------------------------------
// prep: convert x and the 4 weight matrices to bf16 (one kernel).
// blocks [0,1024): x ; then 128 blocks per W.
// ---------------------------------------------------------------------------
__global__ __launch_bounds__(256) void to_bf16_all(
    const float* __restrict__ x,
    const float* __restrict__ wq, const float* __restrict__ wk,
    const float* __restrict__ wv, const float* __restrict__ wo,
    unsigned short* __restrict__ xb,
    unsigned short* __restrict__ wqb, unsigned short* __restrict__ wkb,
    unsigned short* __restrict__ wvb, unsigned short* __restrict__ wob)
{
    const int bid = blockIdx.x;
    const float* src; unsigned short* dst; int idx;
    if (bid < 1024) { src = x; dst = xb; idx = bid; }
    else {
        const int k = (bid - 1024) >> 7;
        idx = (bid - 1024) & 127;
        src = (k == 0) ? wq : (k == 1) ? wk : (k == 2) ? wv : wo;
        dst = (k == 0) ? wqb : (k == 1) ? wkb : (k == 2) ? wvb : wob;
    }
    const int off = idx * 2048 + threadIdx.x * 8;
    float4 a = *(const float4*)(src + off);
    float4 b = *(const float4*)(src + off + 4);
    short8v o;
    o[0] = (short)f2bf(a.x); o[1] = (short)f2bf(a.y);
    o[2] = (short)f2bf(a.z); o[3] = (short)f2bf(a.w);
    o[4] = (short)f2bf(b.x); o[5] = (short)f2bf(b.y);
    o[6] = (short)f2bf(b.z); o[7] = (short)f2bf(b.w);
    *(short8v*)(dst + off) = o;
}

// ---------------------------------------------------------------------------
// bf16 MFMA GEMM: Y[4096,512] = A[4096,512] @ W[512,512]^T + bias  (f32 out)
// 64x64 tile, BK=64, 4 waves (2x2 quadrants of 32x32), LDS swizzled.
// MODE 0: none; 1: also write bf16 sec[h][m][d]; 2: also write bf16 sec[h][d][m].
// ---------------------------------------------------------------------------
template<int MODE>
__global__ __launch_bounds__(256, 2) void gemm512(
    const unsigned short* __restrict__ A,
    const unsigned short* __restrict__ W,
    const float* __restrict__ bias,
    float* __restrict__ Y,
    unsigned short* __restrict__ sec)
{
    __shared__ alignas(16) char sA[8192];
    __shared__ alignas(16) char sB[8192];

    const int t = threadIdx.x;
    const int lane = t & 63, w = t >> 6;
    const int l15 = lane & 15, g4 = lane >> 4;
    const int wr = w >> 1, wc = w & 1;
    const int m0 = blockIdx.y * 64, n0 = blockIdx.x * 64;

    short8v areg[2], breg[2];

#define GL(kk) { _Pragma("unroll") for (int j = 0; j < 2; ++j) { \
        const int unit_ = j * 256 + t, row_ = unit_ >> 3, u_ = unit_ & 7; \
        areg[j] = *(const short8v*)(A + (size_t)(m0 + row_) * 512 + (kk) * 64 + u_ * 8); \
        breg[j] = *(const short8v*)(W + (size_t)(n0 + row_) * 512 + (kk) * 64 + u_ * 8); } }
#define GW() { _Pragma("unroll") for (int j = 0; j < 2; ++j) { \
        const int unit_ = j * 256 + t, row_ = unit_ >> 3, u_ = unit_ & 7; \
        const int byt_ = row_ * 128 + ((u_ ^ (row_ & 7)) * 16); \
        *(short8v*)(sA + byt_) = areg[j]; *(short8v*)(sB + byt_) = breg[j]; } }

    float4v acc[2][2];
#pragma unroll
    for (int mi = 0; mi < 2; ++mi)
#pragma unroll
        for (int ni = 0; ni < 2; ++ni) acc[mi][ni] = (float4v){0.f, 0.f, 0.f, 0.f};

    GL(0); GW(); __syncthreads();

    for (int kk = 0; kk < 8; ++kk) {
        if (kk < 7) GL(kk + 1);
        short8v af[2][2], bf[2][2];
#pragma unroll
        for (int mi = 0; mi < 2; ++mi)
#pragma unroll
            for (int kh = 0; kh < 2; ++kh) {
                const int row = wr * 32 + mi * 16 + l15;
                af[mi][kh] = *(const short8v*)(sA + row * 128 + (((kh * 4 + g4) ^ (l15 & 7)) * 16));
            }
#pragma unroll
        for (int ni = 0; ni < 2; ++ni)
#pragma unroll
            for (int kh = 0; kh < 2; ++kh) {
                const int row = wc * 32 + ni * 16 + l15;
                bf[ni][kh] = *(const short8v*)(sB + row * 128 + (((kh * 4 + g4) ^ (l15 & 7)) * 16));
            }
#pragma unroll
        for (int mi = 0; mi < 2; ++mi)
#pragma unroll
            for (int ni = 0; ni < 2; ++ni) {
                acc[mi][ni] = __builtin_amdgcn_mfma_f32_16x16x32_bf16(af[mi][0], bf[ni][0], acc[mi][ni], 0, 0, 0);
                acc[mi][ni] = __builtin_amdgcn_mfma_f32_16x16x32_bf16(af[mi][1], bf[ni][1], acc[mi][ni], 0, 0, 0);
            }
        __syncthreads();
        if (kk < 7) { GW(); __syncthreads(); }
    }

#pragma unroll
    for (int mi = 0; mi < 2; ++mi)
#pragma unroll
        for (int ni = 0; ni < 2; ++ni) {
            const int col = n0 + wc * 32 + ni * 16 + l15;
            const float bb = bias[col];
#pragma unroll
            for (int r = 0; r < 4; ++r) {
                const int row = m0 + wr * 32 + mi * 16 + g4 * 4 + r;
                const float v = acc[mi][ni][r] + bb;
                Y[(size_t)row * 512 + col] = v;
                if (MODE == 1)
                    sec[((size_t)(col >> 6) * TOK + row) * 64 + (col & 63)] = f2bf(v);
                if (MODE == 2)
                    sec[((size_t)(col >> 6) * 64 + (col & 63)) * TOK + row] = f2bf(v);
            }
        }
#undef GL
#undef GW
}

// ---------------------------------------------------------------------------
// fused attention: block = 64 q-rows (4 waves x 16) of one head.
// K,V chunks (128 m) staged in LDS (reg-carried next chunk = double buffer).
// Pass 1: QK^T -> per-row (max,sum), wave-local. Pass 2: recompute, normalize,
// float4 NT attn store, shuffle-transpose P, PV MFMA from LDS V.
// S^T frag layout (A=K, B=Q): n = lane&15, m = frag_m0 + (lane>>4)*4 + r.
// ---------------------------------------------------------------------------
__global__ __launch_bounds__(256, 2) void fused_attn(
    const float* __restrict__ Q,
    const unsigned short* __restrict__ Kb,   // [H][TOK][64]
    const unsigned short* __restrict__ Vt,   // [H][64][TOK]
    float* __restrict__ attn,
    unsigned short* __restrict__ ctxb)       // [TOK][512] bf16
{
    __shared__ alignas(16) char sK[16384];   // [128 m][128 B] swizzled
    __shared__ alignas(16) char sV[16384];   // [64 d][256 B] swizzled

    const int t = threadIdx.x;
    const int lane = t & 63, w = t >> 6;
    const int l15 = lane & 15, g4 = lane >> 4;
    const int bid = blockIdx.x;
    const int h = bid & 7;                   // head-per-XCD L2 locality
    const int n0 = (bid >> 3) * 64;
    const int nw = n0 + w * 16;

    const unsigned short* KbH = Kb + (size_t)h * TOK * DHEAD;
    const unsigned short* VtH = Vt + (size_t)h * DHEAD * TOK;

    // Q B-fragment (col = n = l15, k = d = g4*8+j), f32 -> bf16
    short8v bq[2];
    {
        const float* qp = Q + (size_t)(nw + l15) * EDIM + h * DHEAD + g4 * 8;
#pragma unroll
        for (int ks = 0; ks < 2; ++ks) {
            float4 u = *(const float4*)(qp + ks * 32);
            float4 v = *(const float4*)(qp + ks * 32 + 4);
            bq[ks][0] = (short)f2bf(u.x); bq[ks][1] = (short)f2bf(u.y);
            bq[ks][2] = (short)f2bf(u.z); bq[ks][3] = (short)f2bf(u.w);
            bq[ks][4] = (short)f2bf(v.x); bq[ks][5] = (short)f2bf(v.y);
            bq[ks][6] = (short)f2bf(v.z); bq[ks][7] = (short)f2bf(v.w);
        }
    }

    short8v kreg[4], vreg[4];
#define LK(c) { _Pragma("unroll") for (int j = 0; j < 4; ++j) { \
        const int unit_ = j * 256 + t, row_ = unit_ >> 3, u_ = unit_ & 7; \
        kreg[j] = *(const short8v*)(KbH + (size_t)((c) * 128 + row_) * 64 + u_ * 8); } }
#define WK() { _Pragma("unroll") for (int j = 0; j < 4; ++j) { \
        const int unit_ = j * 256 + t, row_ = unit_ >> 3, u_ = unit_ & 7; \
        *(short8v*)(sK + row_ * 128 + ((u_ ^ (row_ & 7)) * 16)) = kreg[j]; } }
#define LV(c) { _Pragma("unroll") for (int j = 0; j < 4; ++j) { \
        const int unit_ = j * 256 + t, row_ = unit_ >> 4, u_ = unit_ & 15; \
        vreg[j] = *(const short8v*)(VtH + (size_t)row_ * TOK + (c) * 128 + u_ * 8); } }
#define WV() { _Pragma("unroll") for (int j = 0; j < 4; ++j) { \
        const int unit_ = j * 256 + t, row_ = unit_ >> 4, u_ = unit_ & 15; \
        *(short8v*)(sV + row_ * 256 + ((u_ ^ (row_ & 7)) * 16)) = vreg[j]; } }

    // ================= pass 1: per-row stats =================
    float m2 = -INFINITY;
    float p4[4] = {0.f, 0.f, 0.f, 0.f};

    LK(0); WK(); __syncthreads();
    for (int c = 0; c < 32; ++c) {
        if (c < 31) LK(c + 1);
        float sv[8][4];
        float cm = -INFINITY;
#pragma unroll
        for (int mt = 0; mt < 8; ++mt) {
            const int row = mt * 16 + l15;
            short8v k0 = *(const short8v*)(sK + row * 128 + ((g4 ^ (l15 & 7)) * 16));
            short8v k1 = *(const short8v*)(sK + row * 128 + (((4 + g4) ^ (l15 & 7)) * 16));
            float4v s = (float4v){0.f, 0.f, 0.f, 0.f};
            s = __builtin_amdgcn_mfma_f32_16x16x32_bf16(k0, bq[0], s, 0, 0, 0);
            s = __builtin_amdgcn_mfma_f32_16x16x32_bf16(k1, bq[1], s, 0, 0, 0);
#pragma unroll
            for (int r = 0; r < 4; ++r) { sv[mt][r] = s[r]; cm = fmaxf(cm, s[r]); }
        }
        const float nm = fmaxf(m2, cm);
        const float resc = fast_exp2((m2 - nm) * SC2);
        const float nmc = nm * SC2;
#pragma unroll
        for (int r = 0; r < 4; ++r) p4[r] *= resc;
#pragma unroll
        for (int mt = 0; mt < 8; ++mt)
#pragma unroll
            for (int r = 0; r < 4; ++r)
                p4[r] += fast_exp2(__builtin_fmaf(sv[mt][r], SC2, -nmc));
        m2 = nm;
        __syncthreads();
        if (c < 31) { WK(); __syncthreads(); }
    }

    float srun = (p4[0] + p4[1]) + (p4[2] + p4[3]);
#pragma unroll
    for (int off = 16; off <= 32; off <<= 1) {
        const float om = __shfl_xor(m2, off, 64);
        const float os = __shfl_xor(srun, off, 64);
        const float nm = fmaxf(m2, om);
        srun = srun * fast_exp2((m2 - nm) * SC2) + os * fast_exp2((om - nm) * SC2);
        m2 = nm;
    }
    const float inv = 1.0f / srun;
    const float mq  = m2 * SC2;

    // ================= pass 2: store attn + PV =================
    float* attnH = attn + ((size_t)h * TOK + nw) * TOK;
    float4v cacc[4];
#pragma unroll
    for (int dt = 0; dt < 4; ++dt) cacc[dt] = (float4v){0.f, 0.f, 0.f, 0.f};

    LK(0); LV(0); WK(); WV(); __syncthreads();
    for (int c = 0; c < 32; ++c) {
        if (c < 31) { LK(c + 1); LV(c + 1); }
        const int mbase = c * 128;
        unsigned int u[8][2];
#pragma unroll
        for (int mt = 0; mt < 8; ++mt) {
            const int row = mt * 16 + l15;
            short8v k0 = *(const short8v*)(sK + row * 128 + ((g4 ^ (l15 & 7)) * 16));
            short8v k1 = *(const short8v*)(sK + row * 128 + (((4 + g4) ^ (l15 & 7)) * 16));
            float4v s = (float4v){0.f, 0.f, 0.f, 0.f};
            s = __builtin_amdgcn_mfma_f32_16x16x32_bf16(k0, bq[0], s, 0, 0, 0);
            s = __builtin_amdgcn_mfma_f32_16x16x32_bf16(k1, bq[1], s, 0, 0, 0);
            float4v p;
#pragma unroll
            for (int r = 0; r < 4; ++r)
                p[r] = fast_exp2(__builtin_fmaf(s[r], SC2, -mq)) * inv;
            __builtin_nontemporal_store(
                p, (float4v*)(attnH + (size_t)l15 * TOK + mbase + mt * 16 + g4 * 4));
            u[mt][0] = packbf_tr(p[0], p[1]);
            u[mt][1] = packbf_tr(p[2], p[3]);
        }
#pragma unroll
        for (int ks = 0; ks < 4; ++ks) {
            const int sA = l15 + ((lane & 16) << 1);
            const int sB = sA + 16;
            unsigned int lo0 = __shfl(u[2 * ks][0], sA, 64);
            unsigned int lo1 = __shfl(u[2 * ks][1], sA, 64);
            unsigned int lo2 = __shfl(u[2 * ks][0], sB, 64);
            unsigned int lo3 = __shfl(u[2 * ks][1], sB, 64);
            unsigned int hi0 = __shfl(u[2 * ks + 1][0], sA, 64);
            unsigned int hi1 = __shfl(u[2 * ks + 1][1], sA, 64);
            unsigned int hi2 = __shfl(u[2 * ks + 1][0], sB, 64);
            unsigned int hi3 = __shfl(u[2 * ks + 1][1], sB, 64);
            uint4v wv4;
            const bool sel = (lane & 32) != 0;
            wv4[0] = sel ? hi0 : lo0;
            wv4[1] = sel ? hi1 : lo1;
            wv4[2] = sel ? hi2 : lo2;
            wv4[3] = sel ? hi3 : lo3;
            const short8v pa = __builtin_bit_cast(short8v, wv4);
#pragma unroll
            for (int dt = 0; dt < 4; ++dt) {
                const int rowv = dt * 16 + l15;
                short8v vf = *(const short8v*)(sV + rowv * 256 + (((ks * 4 + g4) ^ (l15 & 7)) * 16));
                cacc[dt] = __builtin_amdgcn_mfma_f32_16x16x32_bf16(pa, vf, cacc[dt], 0, 0, 0);
            }
        }
        __syncthreads();
        if (c < 31) { WK(); WV(); __syncthreads(); }
    }

    // ctx (bf16) for the output projection
#pragma unroll
    for (int dt = 0; dt < 4; ++dt)
#pragma unroll
        for (int r = 0; r < 4; ++r)
            ctxb[(size_t)(nw + g4 * 4 + r) * EDIM + h * DHEAD + dt * 16 + l15] =
                f2bf(cacc[dt][r]);
#undef LK
#undef WK
#undef LV
#undef WV
}

// ---------------------------------------------------------------------------
// launch
// ---------------------------------------------------------------------------
extern "C" void kernel_launch(void* const* d_in, const int* in_sizes, int n_in,
                              void* d_out, int out_size, void* d_ws, size_t ws_size,
                              hipStream_t stream) {
    (void)in_sizes; (void)n_in; (void)out_size; (void)ws_size;

    const float* x  = (const float*)d_in[0];
    const float* Wq = (const float*)d_in[1];
    const float* bq = (const float*)d_in[2];
    const float* Wk = (const float*)d_in[3];
    const float* bk = (const float*)d_in[4];
    const float* Wv = (const float*)d_in[5];
    const float* bv = (const float*)d_in[6];
    const float* Wo = (const float*)d_in[7];
    const float* bo = (const float*)d_in[8];

    float* out  = (float*)d_out;                       // [TOK, EDIM]
    float* attn = out  + (size_t)TOK * EDIM;           // [H, TOK, TOK]
    float* Qf   = attn + (size_t)HEADS * TOK * TOK;    // [TOK, EDIM]
    float* Kf   = Qf   + (size_t)TOK * EDIM;
    float* Vf   = Kf   + (size_t)TOK * EDIM;

    char* wsb = (char*)d_ws;
    unsigned short* xb   = (unsigned short*)wsb;                     // 4 MB (reused as ctxb)
    unsigned short* wqb  = (unsigned short*)(wsb + (4u << 20));
    unsigned short* wkb  = (unsigned short*)(wsb + (4u << 20) + (512u << 10));
    unsigned short* wvb  = (unsigned short*)(wsb + (5u << 20));
    unsigned short* wob  = (unsigned short*)(wsb + (5u << 20) + (512u << 10));
    unsigned short* KbW  = (unsigned short*)(wsb + (6u << 20));      // 4 MB
    unsigned short* VtW  = (unsigned short*)(wsb + (10u << 20));     // 4 MB
    unsigned short* ctxb = xb;

    to_bf16_all<<<1536, 256, 0, stream>>>(x, Wq, Wk, Wv, Wo, xb, wqb, wkb, wvb, wob);

    dim3 gg(EDIM / 64, TOK / 64);
    gemm512<0><<<gg, 256, 0, stream>>>(xb, wqb, bq, Qf, nullptr);
    gemm512<1><<<gg, 256, 0, stream>>>(xb, wkb, bk, Kf, KbW);
    gemm512<2><<<gg, 256, 0, stream>>>(xb, wvb, bv, Vf, VtW);

    fused_attn<<<512, 256, 0, stream>>>(Qf, KbW, VtW, attn, ctxb);

    gemm512<0><<<gg, 256, 0, stream>>>(ctxb, wob, bo, out, nullptr);
}

// Round 5
// 239.999 us; speedup vs baseline: 4.5724x; 1.0280x over previous
//
#include <hip/hip_runtime.h>
#include <hip/hip_bf16.h>
#include <math.h>

#define TOK   4096
#define EDIM  512
#define HEADS 8
#define DHEAD 64

typedef __attribute__((ext_vector_type(8))) short short8v;
typedef __attribute__((ext_vector_type(4))) float float4v;
typedef __attribute__((ext_vector_type(4))) unsigned int uint4v;

#define SC2 0.180336880111f   /* 0.125 * log2(e) */

__device__ __forceinline__ unsigned short f2bf(float f) {
    unsigned int u = __float_as_uint(f);
    unsigned int r = (u + 0x7FFFu + ((u >> 16) & 1u)) >> 16;
    return (unsigned short)r;
}
// pack (truncating round) bf16(lo) | bf16(hi)<<16 in one v_perm_b32
__device__ __forceinline__ unsigned int packbf_tr(float lo, float hi) {
    return __builtin_amdgcn_perm(__float_as_uint(hi), __float_as_uint(lo), 0x07060302u);
}
__device__ __forceinline__ float fast_exp2(float x) {
#if __has_builtin(__builtin_amdgcn_exp2f)
    return __builtin_amdgcn_exp2f(x);
#else
    return __expf(x * 0.69314718f);
#endif
}

// ---------------------------------------------------------------------------
// prep: convert x and the 4 weight matrices to bf16 (one kernel).
// ---------------------------------------------------------------------------
__global__ __launch_bounds__(256) void to_bf16_all(
    const float* __restrict__ x,
    const float* __restrict__ wq, const float* __restrict__ wk,
    const float* __restrict__ wv, const float* __restrict__ wo,
    unsigned short* __restrict__ xb,
    unsigned short* __restrict__ wqb, unsigned short* __restrict__ wkb,
    unsigned short* __restrict__ wvb, unsigned short* __restrict__ wob)
{
    const int bid = blockIdx.x;
    const float* src; unsigned short* dst; int idx;
    if (bid < 1024) { src = x; dst = xb; idx = bid; }
    else {
        const int k = (bid - 1024) >> 7;
        idx = (bid - 1024) & 127;
        src = (k == 0) ? wq : (k == 1) ? wk : (k == 2) ? wv : wo;
        dst = (k == 0) ? wqb : (k == 1) ? wkb : (k == 2) ? wvb : wob;
    }
    const int off = idx * 2048 + threadIdx.x * 8;
    float4 a = *(const float4*)(src + off);
    float4 b = *(const float4*)(src + off + 4);
    short8v o;
    o[0] = (short)f2bf(a.x); o[1] = (short)f2bf(a.y);
    o[2] = (short)f2bf(a.z); o[3] = (short)f2bf(a.w);
    o[4] = (short)f2bf(b.x); o[5] = (short)f2bf(b.y);
    o[6] = (short)f2bf(b.z); o[7] = (short)f2bf(b.w);
    *(short8v*)(dst + off) = o;
}

// ---------------------------------------------------------------------------
// bf16 MFMA GEMM: Y[4096,512] = A[4096,512] @ W[512,512]^T + bias  (f32 out)
// 64x64 tile, BK=64, 4 waves (2x2 quadrants of 32x32), double-buffered LDS,
// 1 barrier per k-step.
// MODE 0: none; 1: also write bf16 sec[h][m][d]; 2: also write bf16 sec[h][d][m].
// ---------------------------------------------------------------------------
template<int MODE>
__global__ __launch_bounds__(256, 3) void gemm512(
    const unsigned short* __restrict__ A,
    const unsigned short* __restrict__ W,
    const float* __restrict__ bias,
    float* __restrict__ Y,
    unsigned short* __restrict__ sec)
{
    __shared__ alignas(16) char sA[2][8192];
    __shared__ alignas(16) char sB[2][8192];

    const int t = threadIdx.x;
    const int lane = t & 63, w = t >> 6;
    const int l15 = lane & 15, g4 = lane >> 4;
    const int wr = w >> 1, wc = w & 1;
    const int m0 = blockIdx.y * 64, n0 = blockIdx.x * 64;

    short8v areg[2], breg[2];

#define GL(kk) { _Pragma("unroll") for (int j = 0; j < 2; ++j) { \
        const int unit_ = j * 256 + t, row_ = unit_ >> 3, u_ = unit_ & 7; \
        areg[j] = *(const short8v*)(A + (size_t)(m0 + row_) * 512 + (kk) * 64 + u_ * 8); \
        breg[j] = *(const short8v*)(W + (size_t)(n0 + row_) * 512 + (kk) * 64 + u_ * 8); } }
#define GW(b) { _Pragma("unroll") for (int j = 0; j < 2; ++j) { \
        const int unit_ = j * 256 + t, row_ = unit_ >> 3, u_ = unit_ & 7; \
        const int byt_ = row_ * 128 + ((u_ ^ (row_ & 7)) * 16); \
        *(short8v*)(sA[b] + byt_) = areg[j]; *(short8v*)(sB[b] + byt_) = breg[j]; } }

    float4v acc[2][2];
#pragma unroll
    for (int mi = 0; mi < 2; ++mi)
#pragma unroll
        for (int ni = 0; ni < 2; ++ni) acc[mi][ni] = (float4v){0.f, 0.f, 0.f, 0.f};

    GL(0); GW(0); __syncthreads();

#pragma unroll 2
    for (int kk = 0; kk < 8; ++kk) {
        if (kk < 7) GL(kk + 1);
        const char* cA = sA[kk & 1];
        const char* cB = sB[kk & 1];
        short8v af[2][2], bf[2][2];
#pragma unroll
        for (int mi = 0; mi < 2; ++mi)
#pragma unroll
            for (int kh = 0; kh < 2; ++kh) {
                const int row = wr * 32 + mi * 16 + l15;
                af[mi][kh] = *(const short8v*)(cA + row * 128 + (((kh * 4 + g4) ^ (l15 & 7)) * 16));
            }
#pragma unroll
        for (int ni = 0; ni < 2; ++ni)
#pragma unroll
            for (int kh = 0; kh < 2; ++kh) {
                const int row = wc * 32 + ni * 16 + l15;
                bf[ni][kh] = *(const short8v*)(cB + row * 128 + (((kh * 4 + g4) ^ (l15 & 7)) * 16));
            }
        __builtin_amdgcn_s_setprio(1);
#pragma unroll
        for (int mi = 0; mi < 2; ++mi)
#pragma unroll
            for (int ni = 0; ni < 2; ++ni) {
                acc[mi][ni] = __builtin_amdgcn_mfma_f32_16x16x32_bf16(af[mi][0], bf[ni][0], acc[mi][ni], 0, 0, 0);
                acc[mi][ni] = __builtin_amdgcn_mfma_f32_16x16x32_bf16(af[mi][1], bf[ni][1], acc[mi][ni], 0, 0, 0);
            }
        __builtin_amdgcn_s_setprio(0);
        if (kk < 7) GW((kk + 1) & 1);
        __syncthreads();
    }

#pragma unroll
    for (int mi = 0; mi < 2; ++mi)
#pragma unroll
        for (int ni = 0; ni < 2; ++ni) {
            const int col = n0 + wc * 32 + ni * 16 + l15;
            const float bb = bias[col];
#pragma unroll
            for (int r = 0; r < 4; ++r) {
                const int row = m0 + wr * 32 + mi * 16 + g4 * 4 + r;
                const float v = acc[mi][ni][r] + bb;
                Y[(size_t)row * 512 + col] = v;
                if (MODE == 1)
                    sec[((size_t)(col >> 6) * TOK + row) * 64 + (col & 63)] = f2bf(v);
                if (MODE == 2)
                    sec[((size_t)(col >> 6) * 64 + (col & 63)) * TOK + row] = f2bf(v);
            }
        }
#undef GL
#undef GW
}

// ---------------------------------------------------------------------------
// fused attention: block = 64 q-rows (4 waves x 16) of one head.
// Pass 1 (sum-only softmax, K double-buffered in LDS, 1 barrier/chunk):
//   QK^T -> per-row sum of exp2(s*SC2).  No max subtraction (|s*SC2| <~ 8,
//   f32 exp2 safe by >30 binades; identical to reference softmax value).
// Pass 2: recompute QK^T, p = exp2(s*SC2)*inv, float4 NT attn store,
//   shuffle-transpose P, PV MFMA from LDS V.
// S^T frag layout (A=K, B=Q): n = lane&15, m = frag_m0 + (lane>>4)*4 + r.
// ---------------------------------------------------------------------------
__global__ __launch_bounds__(256, 3) void fused_attn(
    const float* __restrict__ Q,
    const unsigned short* __restrict__ Kb,   // [H][TOK][64]
    const unsigned short* __restrict__ Vt,   // [H][64][TOK]
    float* __restrict__ attn,
    unsigned short* __restrict__ ctxb)       // [TOK][512] bf16
{
    __shared__ alignas(16) char lds[32768];  // pass1: K dbuf; pass2: sK | sV

    const int t = threadIdx.x;
    const int lane = t & 63, w = t >> 6;
    const int l15 = lane & 15, g4 = lane >> 4;
    const int bid = blockIdx.x;
    const int h = bid & 7;                   // head-per-XCD L2 locality
    const int n0 = (bid >> 3) * 64;
    const int nw = n0 + w * 16;

    const unsigned short* KbH = Kb + (size_t)h * TOK * DHEAD;
    const unsigned short* VtH = Vt + (size_t)h * DHEAD * TOK;

    // Q B-fragment (col = n = l15, k = d = g4*8+j), f32 -> bf16
    short8v bq[2];
    {
        const float* qp = Q + (size_t)(nw + l15) * EDIM + h * DHEAD + g4 * 8;
#pragma unroll
        for (int ks = 0; ks < 2; ++ks) {
            float4 u = *(const float4*)(qp + ks * 32);
            float4 v = *(const float4*)(qp + ks * 32 + 4);
            bq[ks][0] = (short)f2bf(u.x); bq[ks][1] = (short)f2bf(u.y);
            bq[ks][2] = (short)f2bf(u.z); bq[ks][3] = (short)f2bf(u.w);
            bq[ks][4] = (short)f2bf(v.x); bq[ks][5] = (short)f2bf(v.y);
            bq[ks][6] = (short)f2bf(v.z); bq[ks][7] = (short)f2bf(v.w);
        }
    }

    short8v kreg[4], vreg[4];
#define LK(c) { _Pragma("unroll") for (int j = 0; j < 4; ++j) { \
        const int unit_ = j * 256 + t, row_ = unit_ >> 3, u_ = unit_ & 7; \
        kreg[j] = *(const short8v*)(KbH + (size_t)((c) * 128 + row_) * 64 + u_ * 8); } }
#define WK1(b) { _Pragma("unroll") for (int j = 0; j < 4; ++j) { \
        const int unit_ = j * 256 + t, row_ = unit_ >> 3, u_ = unit_ & 7; \
        *(short8v*)(lds + (b) * 16384 + row_ * 128 + ((u_ ^ (row_ & 7)) * 16)) = kreg[j]; } }
#define WK2() { _Pragma("unroll") for (int j = 0; j < 4; ++j) { \
        const int unit_ = j * 256 + t, row_ = unit_ >> 3, u_ = unit_ & 7; \
        *(short8v*)(lds + row_ * 128 + ((u_ ^ (row_ & 7)) * 16)) = kreg[j]; } }
#define LV(c) { _Pragma("unroll") for (int j = 0; j < 4; ++j) { \
        const int unit_ = j * 256 + t, row_ = unit_ >> 4, u_ = unit_ & 15; \
        vreg[j] = *(const short8v*)(VtH + (size_t)row_ * TOK + (c) * 128 + u_ * 8); } }
#define WV() { _Pragma("unroll") for (int j = 0; j < 4; ++j) { \
        const int unit_ = j * 256 + t, row_ = unit_ >> 4, u_ = unit_ & 15; \
        *(short8v*)(lds + 16384 + row_ * 256 + ((u_ ^ (row_ & 7)) * 16)) = vreg[j]; } }

    // ================= pass 1: per-row sum (K dbuf, 1 barrier/chunk) =========
    float p4[4] = {0.f, 0.f, 0.f, 0.f};

    LK(0); WK1(0); __syncthreads();
#pragma unroll 2
    for (int c = 0; c < 32; ++c) {
        if (c < 31) LK(c + 1);
        const char* sKc = lds + (c & 1) * 16384;
#pragma unroll
        for (int mt = 0; mt < 8; ++mt) {
            const int row = mt * 16 + l15;
            short8v k0 = *(const short8v*)(sKc + row * 128 + ((g4 ^ (l15 & 7)) * 16));
            short8v k1 = *(const short8v*)(sKc + row * 128 + (((4 + g4) ^ (l15 & 7)) * 16));
            __builtin_amdgcn_s_setprio(1);
            float4v s = (float4v){0.f, 0.f, 0.f, 0.f};
            s = __builtin_amdgcn_mfma_f32_16x16x32_bf16(k0, bq[0], s, 0, 0, 0);
            s = __builtin_amdgcn_mfma_f32_16x16x32_bf16(k1, bq[1], s, 0, 0, 0);
            __builtin_amdgcn_s_setprio(0);
#pragma unroll
            for (int r = 0; r < 4; ++r)
                p4[r] += fast_exp2(s[r] * SC2);
        }
        if (c < 31) WK1((c + 1) & 1);
        __syncthreads();
    }

    float srun = (p4[0] + p4[1]) + (p4[2] + p4[3]);
#pragma unroll
    for (int off = 16; off <= 32; off <<= 1)
        srun += __shfl_xor(srun, off, 64);
    const float inv = 1.0f / srun;

    // ================= pass 2: store attn + PV =================
    float* attnH = attn + ((size_t)h * TOK + nw) * TOK;
    float4v cacc[4];
#pragma unroll
    for (int dt = 0; dt < 4; ++dt) cacc[dt] = (float4v){0.f, 0.f, 0.f, 0.f};

    LK(0); LV(0); WK2(); WV(); __syncthreads();
    for (int c = 0; c < 32; ++c) {
        if (c < 31) { LK(c + 1); LV(c + 1); }
        const int mbase = c * 128;
        unsigned int u[8][2];
#pragma unroll
        for (int mt = 0; mt < 8; ++mt) {
            const int row = mt * 16 + l15;
            short8v k0 = *(const short8v*)(lds + row * 128 + ((g4 ^ (l15 & 7)) * 16));
            short8v k1 = *(const short8v*)(lds + row * 128 + (((4 + g4) ^ (l15 & 7)) * 16));
            __builtin_amdgcn_s_setprio(1);
            float4v s = (float4v){0.f, 0.f, 0.f, 0.f};
            s = __builtin_amdgcn_mfma_f32_16x16x32_bf16(k0, bq[0], s, 0, 0, 0);
            s = __builtin_amdgcn_mfma_f32_16x16x32_bf16(k1, bq[1], s, 0, 0, 0);
            __builtin_amdgcn_s_setprio(0);
            float4v p;
#pragma unroll
            for (int r = 0; r < 4; ++r)
                p[r] = fast_exp2(s[r] * SC2) * inv;
            __builtin_nontemporal_store(
                p, (float4v*)(attnH + (size_t)l15 * TOK + mbase + mt * 16 + g4 * 4));
            u[mt][0] = packbf_tr(p[0], p[1]);
            u[mt][1] = packbf_tr(p[2], p[3]);
        }
#pragma unroll
        for (int ks = 0; ks < 4; ++ks) {
            const int sA = l15 + ((lane & 16) << 1);
            const int sB = sA + 16;
            unsigned int lo0 = __shfl(u[2 * ks][0], sA, 64);
            unsigned int lo1 = __shfl(u[2 * ks][1], sA, 64);
            unsigned int lo2 = __shfl(u[2 * ks][0], sB, 64);
            unsigned int lo3 = __shfl(u[2 * ks][1], sB, 64);
            unsigned int hi0 = __shfl(u[2 * ks + 1][0], sA, 64);
            unsigned int hi1 = __shfl(u[2 * ks + 1][1], sA, 64);
            unsigned int hi2 = __shfl(u[2 * ks + 1][0], sB, 64);
            unsigned int hi3 = __shfl(u[2 * ks + 1][1], sB, 64);
            uint4v wv4;
            const bool sel = (lane & 32) != 0;
            wv4[0] = sel ? hi0 : lo0;
            wv4[1] = sel ? hi1 : lo1;
            wv4[2] = sel ? hi2 : lo2;
            wv4[3] = sel ? hi3 : lo3;
            const short8v pa = __builtin_bit_cast(short8v, wv4);
            __builtin_amdgcn_s_setprio(1);
#pragma unroll
            for (int dt = 0; dt < 4; ++dt) {
                const int rowv = dt * 16 + l15;
                short8v vf = *(const short8v*)(lds + 16384 + rowv * 256 + (((ks * 4 + g4) ^ (l15 & 7)) * 16));
                cacc[dt] = __builtin_amdgcn_mfma_f32_16x16x32_bf16(pa, vf, cacc[dt], 0, 0, 0);
            }
            __builtin_amdgcn_s_setprio(0);
        }
        __syncthreads();
        if (c < 31) { WK2(); WV(); __syncthreads(); }
    }

    // ctx (bf16) for the output projection
#pragma unroll
    for (int dt = 0; dt < 4; ++dt)
#pragma unroll
        for (int r = 0; r < 4; ++r)
            ctxb[(size_t)(nw + g4 * 4 + r) * EDIM + h * DHEAD + dt * 16 + l15] =
                f2bf(cacc[dt][r]);
#undef LK
#undef WK1
#undef WK2
#undef LV
#undef WV
}

// ---------------------------------------------------------------------------
// launch
// ---------------------------------------------------------------------------
extern "C" void kernel_launch(void* const* d_in, const int* in_sizes, int n_in,
                              void* d_out, int out_size, void* d_ws, size_t ws_size,
                              hipStream_t stream) {
    (void)in_sizes; (void)n_in; (void)out_size; (void)ws_size;

    const float* x  = (const float*)d_in[0];
    const float* Wq = (const float*)d_in[1];
    const float* bq = (const float*)d_in[2];
    const float* Wk = (const float*)d_in[3];
    const float* bk = (const float*)d_in[4];
    const float* Wv = (const float*)d_in[5];
    const float* bv = (const float*)d_in[6];
    const float* Wo = (const float*)d_in[7];
    const float* bo = (const float*)d_in[8];

    float* out  = (float*)d_out;                       // [TOK, EDIM]
    float* attn = out  + (size_t)TOK * EDIM;           // [H, TOK, TOK]
    float* Qf   = attn + (size_t)HEADS * TOK * TOK;    // [TOK, EDIM]
    float* Kf   = Qf   + (size_t)TOK * EDIM;
    float* Vf   = Kf   + (size_t)TOK * EDIM;

    char* wsb = (char*)d_ws;
    unsigned short* xb   = (unsigned short*)wsb;                     // 4 MB (reused as ctxb)
    unsigned short* wqb  = (unsigned short*)(wsb + (4u << 20));
    unsigned short* wkb  = (unsigned short*)(wsb + (4u << 20) + (512u << 10));
    unsigned short* wvb  = (unsigned short*)(wsb + (5u << 20));
    unsigned short* wob  = (unsigned short*)(wsb + (5u << 20) + (512u << 10));
    unsigned short* KbW  = (unsigned short*)(wsb + (6u << 20));      // 4 MB
    unsigned short* VtW  = (unsigned short*)(wsb + (10u << 20));     // 4 MB
    unsigned short* ctxb = xb;

    to_bf16_all<<<1536, 256, 0, stream>>>(x, Wq, Wk, Wv, Wo, xb, wqb, wkb, wvb, wob);

    dim3 gg(EDIM / 64, TOK / 64);
    gemm512<0><<<gg, 256, 0, stream>>>(xb, wqb, bq, Qf, nullptr);
    gemm512<1><<<gg, 256, 0, stream>>>(xb, wkb, bk, Kf, KbW);
    gemm512<2><<<gg, 256, 0, stream>>>(xb, wvb, bv, Vf, VtW);

    fused_attn<<<512, 256, 0, stream>>>(Qf, KbW, VtW, attn, ctxb);

    gemm512<0><<<gg, 256, 0, stream>>>(ctxb, wob, bo, out, nullptr);
}